// Round 1
// baseline (316.252 us; speedup 1.0000x reference)
//
#include <hip/hip_runtime.h>
#include <hip/hip_bf16.h>

// Dynamic per-tensor symmetric int8 quantized GEMM (AQT-style).
//   bound = max(absmax(x), 1e-6); scale = 127/bound
//   q = clip(rint(x*scale), -127, 127)  (int8)
//   out = (q_lhs @ q_rhs) * bound_l*bound_r/127^2   (fp32)
//
// Pipeline (all on `stream`):
//   memset slots -> absmax(lhs) -> absmax(rhs) -> quant(lhs) -> quantT(rhs)
//   -> i8 MFMA GEMM (m97-style 128x128 tile, BT layout, global_load_lds w=16)

typedef int v4i __attribute__((ext_vector_type(4)));

#define MAT_N 4096

__device__ __forceinline__ void async_copy16(const void* g, void* l) {
    __builtin_amdgcn_global_load_lds(
        (const __attribute__((address_space(1))) void*)g,
        (__attribute__((address_space(3))) void*)l,
        16, 0, 0);
}

// ---------------- absmax reduction ----------------
__global__ __launch_bounds__(256) void absmax_kernel(
    const float4* __restrict__ x, int n4, unsigned* __restrict__ slot) {
    unsigned m = 0u;
    for (int i = blockIdx.x * blockDim.x + threadIdx.x; i < n4;
         i += blockDim.x * gridDim.x) {
        float4 v = x[i];
        unsigned a = __float_as_uint(v.x) & 0x7fffffffu;
        unsigned b = __float_as_uint(v.y) & 0x7fffffffu;
        unsigned c = __float_as_uint(v.z) & 0x7fffffffu;
        unsigned d = __float_as_uint(v.w) & 0x7fffffffu;
        m = max(m, max(max(a, b), max(c, d)));
    }
#pragma unroll
    for (int off = 32; off > 0; off >>= 1)
        m = max(m, (unsigned)__shfl_down(m, off, 64));
    __shared__ unsigned sm[4];
    if ((threadIdx.x & 63) == 0) sm[threadIdx.x >> 6] = m;
    __syncthreads();
    if (threadIdx.x == 0) {
        m = max(max(sm[0], sm[1]), max(sm[2], sm[3]));
        atomicMax(slot, m);
    }
}

// ---------------- quantize lhs (row-major passthrough) ----------------
__global__ __launch_bounds__(256) void quant_kernel(
    const float* __restrict__ x, unsigned char* __restrict__ q,
    const unsigned* __restrict__ slot) {
    const float s = 127.0f / fmaxf(__uint_as_float(*slot), 1e-6f);
    const float4* x4 = (const float4*)x;
    unsigned* q4 = (unsigned*)q;
    const int base4 = blockIdx.x * 1024;  // 4096 floats per block
#pragma unroll
    for (int u = 0; u < 4; u++) {
        int idx = base4 + u * 256 + threadIdx.x;
        float4 v = x4[idx];
        int a = min(127, max(-127, (int)rintf(v.x * s)));
        int b = min(127, max(-127, (int)rintf(v.y * s)));
        int c = min(127, max(-127, (int)rintf(v.z * s)));
        int d = min(127, max(-127, (int)rintf(v.w * s)));
        q4[idx] = (unsigned)(a & 0xff) | ((unsigned)(b & 0xff) << 8) |
                  ((unsigned)(c & 0xff) << 16) | ((unsigned)(d & 0xff) << 24);
    }
}

// ---------------- quantize + transpose rhs: [K][N] -> qT[N][K] ----------------
__global__ __launch_bounds__(256) void quantT_kernel(
    const float* __restrict__ x, signed char* __restrict__ qT,
    const unsigned* __restrict__ slot) {
    const int N = MAT_N;
    const float s = 127.0f / fmaxf(__uint_as_float(*slot), 1e-6f);
    __shared__ signed char sm[64][68];  // +4 pad to break bank alignment
    const int k0 = blockIdx.y * 64, n0 = blockIdx.x * 64;
    const int t = threadIdx.x;
    const int n = t & 63, kb = t >> 6;  // kb in [0,4)
#pragma unroll
    for (int r = 0; r < 16; r++) {
        int k = r * 4 + kb;
        float v = x[(size_t)(k0 + k) * N + n0 + n];  // coalesced along n
        int qi = min(127, max(-127, (int)rintf(v * s)));
        sm[k][n] = (signed char)qi;
    }
    __syncthreads();
    const int nn = t >> 2, cb = (t & 3) * 16;
    union { signed char b[16]; int4 v; } tmp;
#pragma unroll
    for (int i = 0; i < 16; i++) tmp.b[i] = sm[cb + i][nn];
    *(int4*)(qT + (size_t)(n0 + nn) * N + k0 + cb) = tmp.v;
}

// ---------------- int8 MFMA GEMM: C = A(MxK) * BT(NxK)^T ----------------
// 128x128 tile / block, 4 waves each computing 64x64 (4x4 of 16x16 MFMA tiles),
// BK=64 (one mfma_i32_16x16x64_i8 K-step per iteration).
__global__ __launch_bounds__(256) void gemm_i8_kernel(
    const signed char* __restrict__ A, const signed char* __restrict__ BT,
    float* __restrict__ C, const unsigned* __restrict__ slots) {
    const int N = MAT_N;
    __shared__ __align__(16) signed char As[128 * 64];
    __shared__ __align__(16) signed char Bs[128 * 64];

    const int tid = threadIdx.x;
    const int wave = tid >> 6;
    const int lane = tid & 63;
    const int quad = lane >> 4;
    const int mrow = lane & 15;
    const int wr = (wave >> 1) * 64;  // wave row offset in tile
    const int wc = (wave & 1) * 64;   // wave col offset in tile
    const int brow = blockIdx.y * 128;
    const int bcol = blockIdx.x * 128;

    v4i acc[4][4] = {};

    // Staging: 512 chunks of 16B per 128x64 tile; chunk c -> row c>>2, byte (c&3)*16.
    // LDS layout row-major [128][64] => lds byte offset of chunk c is exactly c*16,
    // matching global_load_lds's wave-uniform-base + lane*16 placement.
    const int c0 = wave * 64 + lane;  // 0..255 ; second inst adds 256
    const size_t aoff0 = (size_t)(brow + (c0 >> 2)) * N + (c0 & 3) * 16;
    const size_t aoff1 = aoff0 + (size_t)64 * N;
    const size_t boff0 = (size_t)(bcol + (c0 >> 2)) * N + (c0 & 3) * 16;
    const size_t boff1 = boff0 + (size_t)64 * N;
    signed char* a_l0 = As + c0 * 16;
    signed char* a_l1 = As + (c0 + 256) * 16;
    signed char* b_l0 = Bs + c0 * 16;
    signed char* b_l1 = Bs + (c0 + 256) * 16;

    for (int k0 = 0; k0 < N; k0 += 64) {
        __syncthreads();  // previous iteration's ds_reads complete
        async_copy16(A + aoff0 + k0, a_l0);
        async_copy16(A + aoff1 + k0, a_l1);
        async_copy16(BT + boff0 + k0, b_l0);
        async_copy16(BT + boff1 + k0, b_l1);
        __syncthreads();  // vmcnt(0) drain before barrier makes staged data visible

        const v4i* Av = (const v4i*)As;
        const v4i* Bv = (const v4i*)Bs;
        v4i af[4], bf[4];
#pragma unroll
        for (int i = 0; i < 4; i++) af[i] = Av[(wr + i * 16 + mrow) * 4 + quad];
#pragma unroll
        for (int j = 0; j < 4; j++) bf[j] = Bv[(wc + j * 16 + mrow) * 4 + quad];
#pragma unroll
        for (int i = 0; i < 4; i++)
#pragma unroll
            for (int j = 0; j < 4; j++)
                acc[i][j] = __builtin_amdgcn_mfma_i32_16x16x64_i8(
                    af[i], bf[j], acc[i][j], 0, 0, 0);
    }

    // Dequant: out = acc * bound_l*bound_r/127^2
    const float bl = fmaxf(__uint_as_float(slots[0]), 1e-6f);
    const float br = fmaxf(__uint_as_float(slots[1]), 1e-6f);
    const float dq = bl * br * (1.0f / (127.0f * 127.0f));

    // C/D layout (16x16, dtype-independent): col = lane&15, row = quad*4 + reg
#pragma unroll
    for (int i = 0; i < 4; i++) {
        const int row0 = brow + wr + i * 16 + quad * 4;
#pragma unroll
        for (int j = 0; j < 4; j++) {
            const int col = bcol + wc + j * 16 + mrow;
#pragma unroll
            for (int r = 0; r < 4; r++)
                C[(size_t)(row0 + r) * N + col] = (float)acc[i][j][r] * dq;
        }
    }
}

extern "C" void kernel_launch(void* const* d_in, const int* in_sizes, int n_in,
                              void* d_out, int out_size, void* d_ws, size_t ws_size,
                              hipStream_t stream) {
    const float* lhs = (const float*)d_in[0];
    const float* rhs = (const float*)d_in[1];
    float* out = (float*)d_out;

    unsigned* slots = (unsigned*)d_ws;
    signed char* qA = (signed char*)d_ws + 256;
    signed char* qBT = qA + (size_t)MAT_N * MAT_N;

    const int n4 = MAT_N * MAT_N / 4;

    hipMemsetAsync(d_ws, 0, 8, stream);  // zero absmax slots (ws is re-poisoned)
    absmax_kernel<<<2048, 256, 0, stream>>>((const float4*)lhs, n4, slots + 0);
    absmax_kernel<<<2048, 256, 0, stream>>>((const float4*)rhs, n4, slots + 1);
    quant_kernel<<<MAT_N * MAT_N / 4096, 256, 0, stream>>>(
        lhs, (unsigned char*)qA, slots + 0);
    quantT_kernel<<<dim3(64, 64), 256, 0, stream>>>(rhs, qBT, slots + 1);
    gemm_i8_kernel<<<dim3(32, 32), 256, 0, stream>>>(qA, qBT, out, slots);
}

// Round 2
// 278.054 us; speedup vs baseline: 1.1374x; 1.1374x over previous
//
#include <hip/hip_runtime.h>
#include <hip/hip_bf16.h>

// Dynamic per-tensor symmetric int8 quantized GEMM (AQT-style).
//   bound = max(absmax(x), 1e-6); scale = 127/bound
//   q = clip(rint(x*scale), -127, 127)  (int8)
//   out = (q_lhs @ q_rhs) * bound_l*bound_r/127^2   (fp32)
//
// R2: fused prepasses (1 absmax dispatch, 1 quant dispatch), GEMM BK=128 with
// XOR-swizzled LDS chunk placement (swizzle applied on the GLOBAL side since
// global_load_lds forces LDS dst = base + lane*16).

typedef int v4i __attribute__((ext_vector_type(4)));

#define MAT_N 4096

__device__ __forceinline__ void async_copy16(const void* g, void* l) {
    __builtin_amdgcn_global_load_lds(
        (const __attribute__((address_space(1))) void*)g,
        (__attribute__((address_space(3))) void*)l,
        16, 0, 0);
}

__device__ __forceinline__ unsigned uabs_bits(float f) {
    return __float_as_uint(f) & 0x7fffffffu;
}

// ---------------- fused absmax: blocks [0,2048) -> lhs, [2048,4096) -> rhs ---
__global__ __launch_bounds__(256) void absmax2_kernel(
    const float4* __restrict__ lhs, const float4* __restrict__ rhs,
    unsigned* __restrict__ slots) {
    const float4* x = lhs;
    unsigned* slot = slots;
    int b = blockIdx.x;
    if (b >= 2048) { x = rhs; slot = slots + 1; b -= 2048; }
    unsigned m0 = 0, m1 = 0, m2 = 0, m3 = 0;
    int i = b * 256 + threadIdx.x;  // 2048*256 threads, 8 iters covers 4M float4
#pragma unroll
    for (int u = 0; u < 8; u++, i += 524288) {
        float4 v = x[i];
        m0 = max(m0, uabs_bits(v.x));
        m1 = max(m1, uabs_bits(v.y));
        m2 = max(m2, uabs_bits(v.z));
        m3 = max(m3, uabs_bits(v.w));
    }
    unsigned m = max(max(m0, m1), max(m2, m3));
#pragma unroll
    for (int off = 32; off > 0; off >>= 1)
        m = max(m, (unsigned)__shfl_down(m, off, 64));
    __shared__ unsigned sm[4];
    if ((threadIdx.x & 63) == 0) sm[threadIdx.x >> 6] = m;
    __syncthreads();
    if (threadIdx.x == 0) {
        m = max(max(sm[0], sm[1]), max(sm[2], sm[3]));
        atomicMax(slot, m);
    }
}

// ---------------- fused quantize: lhs passthrough + rhs transpose ------------
// blocks [0,4096): lhs block (4096 floats each, row-major -> int8 row-major)
// blocks [4096,8192): rhs 64x64 tile transpose -> qBT[N][K]
__global__ __launch_bounds__(256) void quant_fused_kernel(
    const float* __restrict__ lhs, const float* __restrict__ rhs,
    unsigned char* __restrict__ qA, signed char* __restrict__ qBT,
    const unsigned* __restrict__ slots) {
    const int N = MAT_N;
    const int t = threadIdx.x;
    __shared__ __align__(16) signed char smT[64 * 80];  // [n][k], LDSP=80

    int b = blockIdx.x;
    if (b < 4096) {
        const float s = 127.0f / fmaxf(__uint_as_float(slots[0]), 1e-6f);
        const float4* x4 = (const float4*)lhs;
        unsigned* q4 = (unsigned*)qA;
        const int base4 = b * 1024;
#pragma unroll
        for (int u = 0; u < 4; u++) {
            int idx = base4 + u * 256 + t;
            float4 v = x4[idx];
            int a = min(127, max(-127, (int)rintf(v.x * s)));
            int bq = min(127, max(-127, (int)rintf(v.y * s)));
            int c = min(127, max(-127, (int)rintf(v.z * s)));
            int d = min(127, max(-127, (int)rintf(v.w * s)));
            q4[idx] = (unsigned)(a & 0xff) | ((unsigned)(bq & 0xff) << 8) |
                      ((unsigned)(c & 0xff) << 16) | ((unsigned)(d & 0xff) << 24);
        }
    } else {
        const float s = 127.0f / fmaxf(__uint_as_float(slots[1]), 1e-6f);
        b -= 4096;
        const int n0 = (b & 63) * 64;   // column origin (floats)
        const int k0 = (b >> 6) * 64;   // row origin
        const int mk = t >> 4;          // 0..15 -> k = 4*mk
        const int mn = t & 15;          // 0..15 -> n = 4*mn
        const float4* x4 = (const float4*)rhs;

        unsigned w[4];
#pragma unroll
        for (int i = 0; i < 4; i++) {
            float4 v = x4[(size_t)(k0 + 4 * mk + i) * (N / 4) + (n0 >> 2) + mn];
            int a = min(127, max(-127, (int)rintf(v.x * s)));
            int bq = min(127, max(-127, (int)rintf(v.y * s)));
            int c = min(127, max(-127, (int)rintf(v.z * s)));
            int d = min(127, max(-127, (int)rintf(v.w * s)));
            w[i] = (unsigned)(a & 0xff) | ((unsigned)(bq & 0xff) << 8) |
                   ((unsigned)(c & 0xff) << 16) | ((unsigned)(d & 0xff) << 24);
        }
        // 4x4 byte transpose in registers: u_j = {w0[j], w1[j], w2[j], w3[j]}
#pragma unroll
        for (int j = 0; j < 4; j++) {
            unsigned selj = (unsigned)j | ((unsigned)(4 + j) << 8) |
                            ((unsigned)j << 16) | ((unsigned)(4 + j) << 24);
            unsigned p01 = __builtin_amdgcn_perm(w[1], w[0], selj);
            unsigned p23 = __builtin_amdgcn_perm(w[3], w[2], selj);
            unsigned uj = __builtin_amdgcn_perm(p23, p01, 0x05040100u);
            *(unsigned*)(smT + (4 * mn + j) * 80 + 4 * mk) = uj;
        }
        __syncthreads();
        const int nr = t >> 2;             // 0..63
        const int kq = (t & 3) * 16;       // 0,16,32,48
        int4 val = *(const int4*)(smT + nr * 80 + kq);
        *(int4*)(qBT + (size_t)(n0 + nr) * N + k0 + kq) = val;
    }
}

// ---------------- int8 MFMA GEMM: C = A(MxK) * BT(NxK)^T ----------------
// 128x128 tile / block, 4 waves each 64x64 (4x4 of 16x16 tiles), BK=128.
// LDS chunk swizzle: global chunk (r,q) lives at LDS slot (r, q^(r&7)).
__global__ __launch_bounds__(256) void gemm_i8_kernel(
    const signed char* __restrict__ A, const signed char* __restrict__ BT,
    float* __restrict__ C, const unsigned* __restrict__ slots) {
    const int N = MAT_N;
    __shared__ __align__(16) signed char As[128 * 128];
    __shared__ __align__(16) signed char Bs[128 * 128];

    const int tid = threadIdx.x;
    const int wave = tid >> 6;
    const int lane = tid & 63;
    const int quad = lane >> 4;
    const int mrow = lane & 15;
    const int wr = (wave >> 1) * 64;
    const int wc = (wave & 1) * 64;
    const int brow = blockIdx.y * 128;
    const int bcol = blockIdx.x * 128;

    v4i acc[4][4] = {};

    // Staging: 1024 16B-chunks per 128x128 tile; thread handles c = tid + 256u.
    // LDS slot c = (r=c>>3, q'=c&7) must receive global chunk (r, q'^(r&7)).
    int gaoff[4], gboff[4];
    signed char* la[4];
    signed char* lb[4];
#pragma unroll
    for (int u = 0; u < 4; u++) {
        int c = tid + 256 * u;
        int r = c >> 3;
        int q = (c & 7) ^ (r & 7);
        gaoff[u] = (brow + r) * N + q * 16;
        gboff[u] = (bcol + r) * N + q * 16;
        la[u] = As + c * 16;
        lb[u] = Bs + c * 16;
    }

    for (int k0 = 0; k0 < N; k0 += 128) {
        __syncthreads();  // previous iteration's ds_reads complete
#pragma unroll
        for (int u = 0; u < 4; u++) async_copy16(A + gaoff[u] + k0, la[u]);
#pragma unroll
        for (int u = 0; u < 4; u++) async_copy16(BT + gboff[u] + k0, lb[u]);
        __syncthreads();  // staged data visible

#pragma unroll
        for (int s = 0; s < 2; s++) {
            const int kq = s * 4 + quad;
            v4i af[4], bf[4];
#pragma unroll
            for (int i = 0; i < 4; i++) {
                int r = wr + i * 16 + mrow;
                af[i] = *(const v4i*)(As + (r * 8 + (kq ^ (r & 7))) * 16);
            }
#pragma unroll
            for (int j = 0; j < 4; j++) {
                int r = wc + j * 16 + mrow;
                bf[j] = *(const v4i*)(Bs + (r * 8 + (kq ^ (r & 7))) * 16);
            }
#pragma unroll
            for (int i = 0; i < 4; i++)
#pragma unroll
                for (int j = 0; j < 4; j++)
                    acc[i][j] = __builtin_amdgcn_mfma_i32_16x16x64_i8(
                        af[i], bf[j], acc[i][j], 0, 0, 0);
        }
    }

    const float bl = fmaxf(__uint_as_float(slots[0]), 1e-6f);
    const float br = fmaxf(__uint_as_float(slots[1]), 1e-6f);
    const float dq = bl * br * (1.0f / (127.0f * 127.0f));

    // C/D layout (16x16): col = lane&15, row = quad*4 + reg
#pragma unroll
    for (int i = 0; i < 4; i++) {
        const int row0 = brow + wr + i * 16 + quad * 4;
#pragma unroll
        for (int j = 0; j < 4; j++) {
            const int col = bcol + wc + j * 16 + mrow;
#pragma unroll
            for (int r = 0; r < 4; r++)
                C[(size_t)(row0 + r) * N + col] = (float)acc[i][j][r] * dq;
        }
    }
}

extern "C" void kernel_launch(void* const* d_in, const int* in_sizes, int n_in,
                              void* d_out, int out_size, void* d_ws, size_t ws_size,
                              hipStream_t stream) {
    const float* lhs = (const float*)d_in[0];
    const float* rhs = (const float*)d_in[1];
    float* out = (float*)d_out;

    unsigned* slots = (unsigned*)d_ws;
    signed char* qA = (signed char*)d_ws + 256;
    signed char* qBT = qA + (size_t)MAT_N * MAT_N;

    hipMemsetAsync(d_ws, 0, 8, stream);  // zero absmax slots (ws re-poisoned)
    absmax2_kernel<<<4096, 256, 0, stream>>>(
        (const float4*)lhs, (const float4*)rhs, slots);
    quant_fused_kernel<<<8192, 256, 0, stream>>>(
        lhs, rhs, (unsigned char*)qA, qBT, slots);
    gemm_i8_kernel<<<dim3(32, 32), 256, 0, stream>>>(qA, qBT, out, slots);
}

// Round 3
// 259.971 us; speedup vs baseline: 1.2165x; 1.0696x over previous
//
#include <hip/hip_runtime.h>
#include <hip/hip_bf16.h>

// Dynamic per-tensor symmetric int8 quantized GEMM (AQT-style).
//   bound = max(absmax(x), 1e-6); scale = 127/bound
//   q = clip(rint(x*scale), -127, 127)  (int8)
//   out = (q_lhs @ q_rhs) * bound_l*bound_r/127^2   (fp32)
//
// R3: no-memset pipeline (plain-store partial maxes + in-kernel reduce),
// GEMM on mfma_i32_32x32x32_i8 with v(r)=(r^(r>>3))&7 chunk swizzle
// (applied on the GLOBAL side; global_load_lds forces dst=base+lane*16),
// 8x8 supertile block swizzle.

typedef int v4i __attribute__((ext_vector_type(4)));
typedef int v16i __attribute__((ext_vector_type(16)));

#define MAT_N 4096

__device__ __forceinline__ void async_copy16(const void* g, void* l) {
    __builtin_amdgcn_global_load_lds(
        (const __attribute__((address_space(1))) void*)g,
        (__attribute__((address_space(3))) void*)l,
        16, 0, 0);
}

__device__ __forceinline__ unsigned uabs_bits(float f) {
    return __float_as_uint(f) & 0x7fffffffu;
}

// ---- absmax partials: blocks [0,512) lhs, [512,1024) rhs; pmax[b] plain store
__global__ __launch_bounds__(256) void absmax_partial_kernel(
    const float4* __restrict__ lhs, const float4* __restrict__ rhs,
    unsigned* __restrict__ pmax) {
    const int b = blockIdx.x;
    const float4* x = (b < 512) ? lhs : rhs;
    const float4* p = x + (size_t)(b & 511) * 8192;
    unsigned m0 = 0, m1 = 0, m2 = 0, m3 = 0;
#pragma unroll 8
    for (int u = 0; u < 32; u++) {
        float4 v = p[u * 256 + threadIdx.x];
        m0 = max(m0, uabs_bits(v.x));
        m1 = max(m1, uabs_bits(v.y));
        m2 = max(m2, uabs_bits(v.z));
        m3 = max(m3, uabs_bits(v.w));
    }
    unsigned m = max(max(m0, m1), max(m2, m3));
#pragma unroll
    for (int off = 32; off > 0; off >>= 1)
        m = max(m, (unsigned)__shfl_down(m, off, 64));
    __shared__ unsigned sm[4];
    if ((threadIdx.x & 63) == 0) sm[threadIdx.x >> 6] = m;
    __syncthreads();
    if (threadIdx.x == 0)
        pmax[b] = max(max(sm[0], sm[1]), max(sm[2], sm[3]));
}

// ---- fused quantize: blocks [0,4096) lhs passthrough; [4096,8192) rhs transpose
__global__ __launch_bounds__(256) void quant_fused_kernel(
    const float* __restrict__ lhs, const float* __restrict__ rhs,
    unsigned char* __restrict__ qA, signed char* __restrict__ qBT,
    const unsigned* __restrict__ pmax) {
    const int N = MAT_N;
    const int t = threadIdx.x;
    int b = blockIdx.x;
    __shared__ __align__(16) signed char smT[64 * 80];  // [n][k], LDSP=80
    __shared__ unsigned red[4];
    __shared__ float s_sh;

    // Reduce this tensor's 512 partials -> scale (L2-hot, ~2KB)
    const int slot0 = (b < 4096) ? 0 : 512;
    unsigned mm = max(pmax[slot0 + t], pmax[slot0 + 256 + t]);
#pragma unroll
    for (int off = 32; off > 0; off >>= 1)
        mm = max(mm, (unsigned)__shfl_down(mm, off, 64));
    if ((t & 63) == 0) red[t >> 6] = mm;
    __syncthreads();
    if (t == 0) {
        unsigned f = max(max(red[0], red[1]), max(red[2], red[3]));
        s_sh = 127.0f / fmaxf(__uint_as_float(f), 1e-6f);
    }
    __syncthreads();
    const float s = s_sh;

    if (b < 4096) {
        const float4* x4 = (const float4*)lhs;
        unsigned* q4 = (unsigned*)qA;
        const int base4 = b * 1024;
#pragma unroll
        for (int u = 0; u < 4; u++) {
            int idx = base4 + u * 256 + t;
            float4 v = x4[idx];
            int a = min(127, max(-127, (int)rintf(v.x * s)));
            int bq = min(127, max(-127, (int)rintf(v.y * s)));
            int c = min(127, max(-127, (int)rintf(v.z * s)));
            int d = min(127, max(-127, (int)rintf(v.w * s)));
            q4[idx] = (unsigned)(a & 0xff) | ((unsigned)(bq & 0xff) << 8) |
                      ((unsigned)(c & 0xff) << 16) | ((unsigned)(d & 0xff) << 24);
        }
    } else {
        b -= 4096;
        const int n0 = (b & 63) * 64;   // column origin (floats)
        const int k0 = (b >> 6) * 64;   // row origin
        const int mk = t >> 4;          // 0..15 -> k = 4*mk
        const int mn = t & 15;          // 0..15 -> n = 4*mn
        const float4* x4 = (const float4*)rhs;

        unsigned w[4];
#pragma unroll
        for (int i = 0; i < 4; i++) {
            float4 v = x4[(size_t)(k0 + 4 * mk + i) * (N / 4) + (n0 >> 2) + mn];
            int a = min(127, max(-127, (int)rintf(v.x * s)));
            int bq = min(127, max(-127, (int)rintf(v.y * s)));
            int c = min(127, max(-127, (int)rintf(v.z * s)));
            int d = min(127, max(-127, (int)rintf(v.w * s)));
            w[i] = (unsigned)(a & 0xff) | ((unsigned)(bq & 0xff) << 8) |
                   ((unsigned)(c & 0xff) << 16) | ((unsigned)(d & 0xff) << 24);
        }
        // 4x4 byte transpose in registers
#pragma unroll
        for (int j = 0; j < 4; j++) {
            unsigned selj = (unsigned)j | ((unsigned)(4 + j) << 8) |
                            ((unsigned)j << 16) | ((unsigned)(4 + j) << 24);
            unsigned p01 = __builtin_amdgcn_perm(w[1], w[0], selj);
            unsigned p23 = __builtin_amdgcn_perm(w[3], w[2], selj);
            unsigned uj = __builtin_amdgcn_perm(p23, p01, 0x05040100u);
            *(unsigned*)(smT + (4 * mn + j) * 80 + 4 * mk) = uj;
        }
        __syncthreads();
        const int nr = t >> 2;
        const int kq = (t & 3) * 16;
        int4 val = *(const int4*)(smT + nr * 80 + kq);
        *(int4*)(qBT + (size_t)(n0 + nr) * N + k0 + kq) = val;
    }
}

// ---- int8 MFMA GEMM: C = A(MxK) * BT(NxK)^T, 128x128 tile, BK=128,
// mfma_i32_32x32x32_i8, wave tile 64x64 = 2x2 of 32x32.
// LDS chunk swizzle v(r)=(r^(r>>3))&7: global chunk (r,q) -> LDS slot (r, q^v(r)).
__global__ __launch_bounds__(256) void gemm_i8_kernel(
    const signed char* __restrict__ A, const signed char* __restrict__ BT,
    float* __restrict__ C, const unsigned* __restrict__ pmax) {
    const int N = MAT_N;
    __shared__ __align__(16) signed char As[128 * 128];
    __shared__ __align__(16) signed char Bs[128 * 128];

    const int tid = threadIdx.x;
    const int wave = tid >> 6;
    const int lane = tid & 63;
    const int m32 = lane & 31;   // row/col within a 32-tile
    const int h = lane >> 5;     // k-half selector
    const int wr = (wave >> 1) * 64;
    const int wc = (wave & 1) * 64;

    // 8x8 supertile swizzle over the 32x32 block grid
    const int flat = blockIdx.x;
    const int super = flat >> 6;        // 16 supertiles
    const int within = flat & 63;
    const int bx = (super & 3) * 8 + (within & 7);
    const int by = (super >> 2) * 8 + (within >> 3);
    const int brow = by * 128;
    const int bcol = bx * 128;

    v16i acc[2][2] = {};

    // Staging: 1024 16B-chunks per 128x128 tile; LDS slot c=(r=c>>3, q'=c&7)
    // receives global chunk q = q' ^ v(r).
    int gaoff[4], gboff[4];
    signed char* la[4];
    signed char* lb[4];
#pragma unroll
    for (int u = 0; u < 4; u++) {
        int c = tid + 256 * u;
        int r = c >> 3;
        int q = (c & 7) ^ ((r ^ (r >> 3)) & 7);
        gaoff[u] = (brow + r) * N + q * 16;
        gboff[u] = (bcol + r) * N + q * 16;
        la[u] = As + c * 16;
        lb[u] = Bs + c * 16;
    }

    // Precompute fragment row bases + swizzle keys (k0/s-invariant)
    int abase[2], avr[2], bbase[2], bvr[2];
#pragma unroll
    for (int i = 0; i < 2; i++) {
        int r = wr + i * 32 + m32;
        abase[i] = r * 8;
        avr[i] = (r ^ (r >> 3)) & 7;
        r = wc + i * 32 + m32;
        bbase[i] = r * 8;
        bvr[i] = (r ^ (r >> 3)) & 7;
    }

    for (int k0 = 0; k0 < N; k0 += 128) {
        __syncthreads();
#pragma unroll
        for (int u = 0; u < 4; u++) async_copy16(A + gaoff[u] + k0, la[u]);
#pragma unroll
        for (int u = 0; u < 4; u++) async_copy16(BT + gboff[u] + k0, lb[u]);
        __syncthreads();

#pragma unroll
        for (int s = 0; s < 4; s++) {
            const int q = 2 * s + h;  // 16B chunk index of this lane's k-slice
            v4i af[2], bf[2];
#pragma unroll
            for (int i = 0; i < 2; i++)
                af[i] = *(const v4i*)(As + (abase[i] + (q ^ avr[i])) * 16);
#pragma unroll
            for (int j = 0; j < 2; j++)
                bf[j] = *(const v4i*)(Bs + (bbase[j] + (q ^ bvr[j])) * 16);
#pragma unroll
            for (int i = 0; i < 2; i++)
#pragma unroll
                for (int j = 0; j < 2; j++)
                    acc[i][j] = __builtin_amdgcn_mfma_i32_32x32x32_i8(
                        af[i], bf[j], acc[i][j], 0, 0, 0);
        }
    }

    // Dequant scales from partials (already reduced per-tensor? no: reduce here
    // cheaply — 512 values, but only need final: recompute via 8 loads/lane)
    // Simpler: lane 0 of each... use full reduction like quant preamble.
    __shared__ unsigned redl[4], redr[4];
    unsigned ml = max(pmax[tid], pmax[tid + 256]);
    unsigned mr = max(pmax[512 + tid], pmax[768 + tid]);
#pragma unroll
    for (int off = 32; off > 0; off >>= 1) {
        ml = max(ml, (unsigned)__shfl_down(ml, off, 64));
        mr = max(mr, (unsigned)__shfl_down(mr, off, 64));
    }
    if (lane == 0) { redl[wave] = ml; redr[wave] = mr; }
    __syncthreads();
    const float bl = fmaxf(
        __uint_as_float(max(max(redl[0], redl[1]), max(redl[2], redl[3]))), 1e-6f);
    const float br = fmaxf(
        __uint_as_float(max(max(redr[0], redr[1]), max(redr[2], redr[3]))), 1e-6f);
    const float dq = bl * br * (1.0f / (127.0f * 127.0f));

    // C/D layout (32x32): col = lane&31, row = (reg&3) + 8*(reg>>2) + 4*h
#pragma unroll
    for (int i = 0; i < 2; i++)
#pragma unroll
        for (int j = 0; j < 2; j++) {
            const int col = bcol + wc + j * 32 + m32;
#pragma unroll
            for (int reg = 0; reg < 16; reg++) {
                const int row =
                    brow + wr + i * 32 + (reg & 3) + 8 * (reg >> 2) + 4 * h;
                C[(size_t)row * N + col] = (float)acc[i][j][reg] * dq;
            }
        }
}

extern "C" void kernel_launch(void* const* d_in, const int* in_sizes, int n_in,
                              void* d_out, int out_size, void* d_ws, size_t ws_size,
                              hipStream_t stream) {
    const float* lhs = (const float*)d_in[0];
    const float* rhs = (const float*)d_in[1];
    float* out = (float*)d_out;

    unsigned* pmax = (unsigned*)d_ws;  // 1024 partials (all written each call)
    signed char* qA = (signed char*)d_ws + 8192;
    signed char* qBT = qA + (size_t)MAT_N * MAT_N;

    absmax_partial_kernel<<<1024, 256, 0, stream>>>(
        (const float4*)lhs, (const float4*)rhs, pmax);
    quant_fused_kernel<<<8192, 256, 0, stream>>>(
        lhs, rhs, (unsigned char*)qA, qBT, pmax);
    gemm_i8_kernel<<<1024, 256, 0, stream>>>(qA, qBT, out, pmax);
}